// Round 6
// baseline (11017.081 us; speedup 1.0000x reference)
//
#include <hip/hip_runtime.h>

// ---------------- problem constants ----------------
#define T_STEPS 256
#define BATCH   64
#define DIN     512
#define HID     1024
#define NCOLS   4096   // 4*HID
#define NBLK    256    // persistent blocks (1 per CU)
#define TPB     512    // 8 waves: waves 0-3 = layer0, waves 4-7 = layer1

typedef __attribute__((ext_vector_type(8))) short short8;
typedef __attribute__((ext_vector_type(4))) float float4v;
typedef unsigned long long u64;

union Frag { u64 u[2]; short8 s; };

__device__ __forceinline__ short f2bf(float x) {
    unsigned u = __float_as_uint(x);
    u += 0x7FFFu + ((u >> 16) & 1u);   // RNE
    return (short)(u >> 16);
}
__device__ __forceinline__ float sigmoidf_(float x) { return 1.0f / (1.0f + __expf(-x)); }
__device__ __forceinline__ float tanhf_(float x)    { return 1.0f - 2.0f / (__expf(2.0f * x) + 1.0f); }

// ---------------- prologue kernels ----------------
__global__ void cvt_bf16_kernel(const float* __restrict__ src, short* __restrict__ dst, int n) {
    int i = blockIdx.x * blockDim.x + threadIdx.x;
    int stride = gridDim.x * blockDim.x;
    for (; i < n; i += stride) dst[i] = f2bf(src[i]);
}

// src: R x C fp32 row-major -> dst: C x R bf16 row-major
__global__ void transpose_bf16_kernel(const float* __restrict__ src, short* __restrict__ dst,
                                      int R, int C) {
    __shared__ float tile[32][33];
    int tx = threadIdx.x, ty = threadIdx.y;
    int r0 = blockIdx.y * 32, c0 = blockIdx.x * 32;
#pragma unroll
    for (int i = 0; i < 32; i += 8)
        tile[ty + i][tx] = src[(size_t)(r0 + ty + i) * C + (c0 + tx)];
    __syncthreads();
#pragma unroll
    for (int i = 0; i < 32; i += 8)
        dst[(size_t)(c0 + ty + i) * R + (r0 + tx)] = f2bf(tile[tx][ty + i]);
}

// ---------------- fused persistent LSTM, wave-group layer-parallel ----------
// Round-5 analysis: per-step body ~13us serial (latency-bound: sunk bypass
// loads -> MFMA dependent chain), barrier only ~1.2us, at 1 wave/SIMD there
// is no TLP to hide it. Fix: TPB=512 (2 waves/SIMD); waves 0-3 run layer 0's
// step body, waves 4-7 run layer 1's CONCURRENTLY (they only depend on
// barrier-protected h0(s-1)/h1(s-2), never on each other intra-step).
// Per-superstep ~= max(L0,L1) + barrier instead of L0+L1+barrier.
// Both groups execute one unified body => identical __syncthreads sequence.
//
// Weights: Whh1 staged in LDS (32 KB, fragment order, conflict-free reads);
// Wih0/Whh0/Wih1 streamed from L2 (2.6 MB/XCD < 4 MiB -- round-5-proven).
//
// Communication substrate unchanged (proven): parity double-buffers h0A/B,
// h1A/B, memset-zeroed; bypass atomic stores + s_waitcnt(0) drain before
// flag; bypass atomic loads; monotonic flag counters + poll.
// Workspace 46.7 MB (proven budget).
__global__ __launch_bounds__(TPB, 2) void lstm_persist(
    const int* __restrict__ length,
    const float* __restrict__ b0,  const float* __restrict__ g_ih0, const float* __restrict__ bt_ih0,
    const float* __restrict__ g_hh0, const float* __restrict__ bt_hh0,
    const float* __restrict__ g_c0,  const float* __restrict__ bt_c0,
    const float* __restrict__ b1,  const float* __restrict__ g_ih1, const float* __restrict__ bt_ih1,
    const float* __restrict__ g_hh1, const float* __restrict__ bt_hh1,
    const float* __restrict__ g_c1,  const float* __restrict__ bt_c1,
    const short* __restrict__ xb,
    const short* __restrict__ wih0T, const short* __restrict__ whh0T,
    const short* __restrict__ wih1T, const short* __restrict__ whh1T,
    short* __restrict__ h0A, short* __restrict__ h0B,
    short* __restrict__ h1A, short* __restrict__ h1B,
    unsigned* __restrict__ flags,
    float* __restrict__ out)
{
    const int wg   = blockIdx.x;
    const int tid  = threadIdx.x;
    const int wave = tid >> 6;
    const int lane = tid & 63;
    const int nidx = lane & 15;
    const int quad = lane >> 4;
    const int grp  = wave >> 2;          // 0 = layer0, 1 = layer1
    const int rg   = wave & 3;           // row group within the layer

    __shared__ short8 Lh1s[2048];        // Whh1 slice, 32 KB (frag order)
    __shared__ float st_s[8][16][17];    // per-wave 16x16 s tile (+pad)
    __shared__ float red_h[8][16][2];    // per-wave column (sum,sumsq) hh
    __shared__ float red_i[8][16][2];    // ... ih
    __shared__ float red_c[8][4][2];     // per-wave (sum,sumsq) for c, 4 j's
    __shared__ unsigned okv[8];          // barrier poll combine

    const int ncol  = wg * 4 + (nidx & 3) + (nidx >> 2) * HID;  // s-col 0..4095
    const int m_row = rg * 16 + nidx;    // A-fragment batch row

    const int mc   = lane & 15;          // c-phase: row within wave
    const int jc   = quad;               // c-phase: which of 4 j's
    const int m_cg = rg * 16 + mc;
    const int j_g  = wg * 4 + jc;
    const int len_c = length[m_cg];
    const float inv64 = 1.0f / 64.0f;

    // ---- one-time LDS staging: Whh1 fragments (f = e*16 + n) ----
    for (int idx = tid; idx < 2048; idx += TPB) {
        int e = idx & 127, n = idx >> 7;
        int ncol_n = wg * 4 + (n & 3) + (n >> 2) * HID;
        Lh1s[e * 16 + n] = ((const short8*)whh1T)[(size_t)ncol_n * 128 + e];
    }
    __syncthreads();

    const int b_off = quad * 16 + nidx;  // LDS fragment offset: kk*64 + b_off

    // streamed B pointers (L2-resident)
    const short8* Bih  = (const short8*)(grp ? wih1T : wih0T)
                         + (size_t)ncol * ((grp ? HID : DIN) / 8) + quad;
    const short8* Bh0p = (const short8*)whh0T + (size_t)ncol * (HID / 8) + quad;

    // per-group BN / bias params
    const float gihv = (grp ? g_ih1  : g_ih0 )[ncol];
    const float btih = (grp ? bt_ih1 : bt_ih0)[ncol];
    const float ghhv = (grp ? g_hh1  : g_hh0)[ncol];
    const float bthh = (grp ? bt_hh1 : bt_hh0)[ncol];
    const float bbv  = (grp ? b1     : b0   )[ncol];
    const float gcv  = (grp ? g_c1   : g_c0 )[j_g];
    const float btc  = (grp ? bt_c1  : bt_c0)[j_g];

    float h_st = 0.f, c_st = 0.f;        // this thread's layer-(grp) state

#pragma unroll 1
    for (int s = 0; s <= T_STEPS; ++s) {
        const int p = s & 1;
        const short* h0r = p ? h0A : h0B;   // h0(s-1)   (zeroed at s=0)
        short*       h0w = p ? h0B : h0A;   // <- h0(s)
        const short* h1r = p ? h1B : h1A;   // h1(s-2)   (zeroed at s<=1)
        short*       h1w = p ? h1A : h1B;   // <- h1(s-1)

        // ---- pre-barrier: grp0's ih0 GEMM (x cached, Wih0 streamed) ----
        float4v acc_i = {0.f, 0.f, 0.f, 0.f};
        if (grp == 0 && s < T_STEPS) {
            const short8* Axp = (const short8*)xb + (((size_t)(s * BATCH + m_row) * DIN) >> 3) + quad;
            float4v a0 = {0.f,0.f,0.f,0.f}, a1 = {0.f,0.f,0.f,0.f};
#pragma unroll
            for (int kk = 0; kk < 16; ++kk) {
                if (kk & 1) a1 = __builtin_amdgcn_mfma_f32_16x16x32_bf16(Axp[kk * 4], Bih[kk * 4], a1, 0, 0, 0);
                else        a0 = __builtin_amdgcn_mfma_f32_16x16x32_bf16(Axp[kk * 4], Bih[kk * 4], a0, 0, 0, 0);
            }
            acc_i = a0 + a1;
        }

        // ---- grid barrier: all blocks finished superstep s-1 ----
        if (s > 0) {
            const unsigned need = (unsigned)s;
            for (;;) {
                unsigned f = __hip_atomic_load(&flags[(tid & 255) * 4], __ATOMIC_RELAXED,
                                               __HIP_MEMORY_SCOPE_AGENT);
                unsigned long long bal = __ballot(f >= need);
                if (lane == 0) okv[wave] = (bal + 1ull == 0ull);
                __syncthreads();
                bool all8 = okv[0] && okv[1] && okv[2] && okv[3]
                         && okv[4] && okv[5] && okv[6] && okv[7];
                __syncthreads();
                if (all8) break;
                __builtin_amdgcn_s_sleep(2);
            }
            asm volatile("" ::: "memory");   // no load motion across the barrier
        }

        // ---- post-barrier GEMMs (bypass loads of h state) ----
        float4v acc_h = {0.f,0.f,0.f,0.f};
        if (grp == 0) {
            // hh0: A = h0(s-1), B = Whh0 streamed
            u64 A2[64];
            const u64* hp = (const u64*)h0r + (size_t)m_row * (HID / 4) + quad * 2;
#pragma unroll
            for (int kk = 0; kk < 32; ++kk) {
                A2[2 * kk]     = __hip_atomic_load(hp + kk * 8,     __ATOMIC_RELAXED, __HIP_MEMORY_SCOPE_AGENT);
                A2[2 * kk + 1] = __hip_atomic_load(hp + kk * 8 + 1, __ATOMIC_RELAXED, __HIP_MEMORY_SCOPE_AGENT);
            }
            float4v h0a = {0.f,0.f,0.f,0.f}, h0b = {0.f,0.f,0.f,0.f};
#pragma unroll
            for (int kk = 0; kk < 32; ++kk) {
                Frag fa; fa.u[0] = A2[2 * kk]; fa.u[1] = A2[2 * kk + 1];
                if (kk & 1) h0b = __builtin_amdgcn_mfma_f32_16x16x32_bf16(fa.s, Bh0p[kk * 4], h0b, 0, 0, 0);
                else        h0a = __builtin_amdgcn_mfma_f32_16x16x32_bf16(fa.s, Bh0p[kk * 4], h0a, 0, 0, 0);
            }
            acc_h = h0a + h0b;
        } else {
            // ih1: A = h0(s-1) (=y0(t1)), B = Wih1 streamed
            // hh1: A = h1(s-2),           B = Whh1 from LDS
            u64 A2[64];
            u64 C2[64];
            const u64* hp = (const u64*)h0r + (size_t)m_row * (HID / 4) + quad * 2;
            const u64* cp = (const u64*)h1r + (size_t)m_row * (HID / 4) + quad * 2;
#pragma unroll
            for (int kk = 0; kk < 32; ++kk) {
                A2[2 * kk]     = __hip_atomic_load(hp + kk * 8,     __ATOMIC_RELAXED, __HIP_MEMORY_SCOPE_AGENT);
                A2[2 * kk + 1] = __hip_atomic_load(hp + kk * 8 + 1, __ATOMIC_RELAXED, __HIP_MEMORY_SCOPE_AGENT);
            }
#pragma unroll
            for (int kk = 0; kk < 32; ++kk) {
                C2[2 * kk]     = __hip_atomic_load(cp + kk * 8,     __ATOMIC_RELAXED, __HIP_MEMORY_SCOPE_AGENT);
                C2[2 * kk + 1] = __hip_atomic_load(cp + kk * 8 + 1, __ATOMIC_RELAXED, __HIP_MEMORY_SCOPE_AGENT);
            }
            float4v i1a = {0.f,0.f,0.f,0.f}, i1b = {0.f,0.f,0.f,0.f};
#pragma unroll
            for (int kk = 0; kk < 32; ++kk) {
                Frag fa; fa.u[0] = A2[2 * kk]; fa.u[1] = A2[2 * kk + 1];
                if (kk & 1) i1b = __builtin_amdgcn_mfma_f32_16x16x32_bf16(fa.s, Bih[kk * 4], i1b, 0, 0, 0);
                else        i1a = __builtin_amdgcn_mfma_f32_16x16x32_bf16(fa.s, Bih[kk * 4], i1a, 0, 0, 0);
            }
            acc_i = i1a + i1b;
            float4v ha = {0.f,0.f,0.f,0.f}, hb = {0.f,0.f,0.f,0.f};
            float4v hc = {0.f,0.f,0.f,0.f}, hd = {0.f,0.f,0.f,0.f};
#pragma unroll
            for (int kk = 0; kk < 32; ++kk) {
                Frag fa; fa.u[0] = C2[2 * kk]; fa.u[1] = C2[2 * kk + 1];
                short8 bh = Lh1s[kk * 64 + b_off];
                switch (kk & 3) {
                    case 0:  ha = __builtin_amdgcn_mfma_f32_16x16x32_bf16(fa.s, bh, ha, 0, 0, 0); break;
                    case 1:  hb = __builtin_amdgcn_mfma_f32_16x16x32_bf16(fa.s, bh, hb, 0, 0, 0); break;
                    case 2:  hc = __builtin_amdgcn_mfma_f32_16x16x32_bf16(fa.s, bh, hc, 0, 0, 0); break;
                    default: hd = __builtin_amdgcn_mfma_f32_16x16x32_bf16(fa.s, bh, hd, 0, 0, 0); break;
                }
            }
            acc_h = (ha + hb) + (hc + hd);
        }

        // ========== unified BN + gates (identical sync sequence, both grps) ==========
        {
            float s1h = acc_h[0] + acc_h[1] + acc_h[2] + acc_h[3];
            float s2h = acc_h[0]*acc_h[0] + acc_h[1]*acc_h[1] + acc_h[2]*acc_h[2] + acc_h[3]*acc_h[3];
            float s1i = acc_i[0] + acc_i[1] + acc_i[2] + acc_i[3];
            float s2i = acc_i[0]*acc_i[0] + acc_i[1]*acc_i[1] + acc_i[2]*acc_i[2] + acc_i[3]*acc_i[3];
            s1h += __shfl_xor(s1h, 16); s1h += __shfl_xor(s1h, 32);
            s2h += __shfl_xor(s2h, 16); s2h += __shfl_xor(s2h, 32);
            s1i += __shfl_xor(s1i, 16); s1i += __shfl_xor(s1i, 32);
            s2i += __shfl_xor(s2i, 16); s2i += __shfl_xor(s2i, 32);
            if (quad == 0) {
                red_h[wave][nidx][0] = s1h; red_h[wave][nidx][1] = s2h;
                red_i[wave][nidx][0] = s1i; red_i[wave][nidx][1] = s2i;
            }
            __syncthreads();
            float th = 0.f, qh = 0.f, ti = 0.f, qi = 0.f;
#pragma unroll
            for (int w = 0; w < 4; ++w) {
                th += red_h[grp * 4 + w][nidx][0]; qh += red_h[grp * 4 + w][nidx][1];
                ti += red_i[grp * 4 + w][nidx][0]; qi += red_i[grp * 4 + w][nidx][1];
            }
            float muh = th * inv64, vah = qh * inv64 - muh * muh;
            float mui = ti * inv64, vai = qi * inv64 - mui * mui;
            float rsh = rsqrtf(vah + 1e-5f), rsi = rsqrtf(vai + 1e-5f);
#pragma unroll
            for (int r = 0; r < 4; ++r) {
                float sv = ghhv * (acc_h[r] - muh) * rsh + bthh
                         + gihv * (acc_i[r] - mui) * rsi + btih + bbv;
                st_s[wave][quad * 4 + r][nidx] = sv;
            }
            __syncthreads();

            float fv = st_s[wave][mc][jc];
            float iv = st_s[wave][mc][4 + jc];
            float ov = st_s[wave][mc][8 + jc];
            float gv = st_s[wave][mc][12 + jc];
            float c1 = sigmoidf_(fv) * c_st + sigmoidf_(iv) * tanhf_(gv);

            float cs = c1, cq = c1 * c1;
            cs += __shfl_xor(cs, 1); cs += __shfl_xor(cs, 2);
            cs += __shfl_xor(cs, 4); cs += __shfl_xor(cs, 8);
            cq += __shfl_xor(cq, 1); cq += __shfl_xor(cq, 2);
            cq += __shfl_xor(cq, 4); cq += __shfl_xor(cq, 8);
            if (mc == 0) { red_c[wave][jc][0] = cs; red_c[wave][jc][1] = cq; }
            __syncthreads();
            float tc = 0.f, qc = 0.f;
#pragma unroll
            for (int w = 0; w < 4; ++w) { tc += red_c[grp * 4 + w][jc][0]; qc += red_c[grp * 4 + w][jc][1]; }
            float muc = tc * inv64, vac = qc * inv64 - muc * muc;
            float bnc = gcv * (c1 - muc) * rsqrtf(vac + 1e-5f) + btc;
            float h1v = sigmoidf_(ov) * tanhf_(bnc);

            const int tt = grp ? (s - 1) : s;       // this group's timestep
            bool mk = (tt >= 0) && (tt < len_c);
            h_st = mk ? h1v : h_st;
            c_st = mk ? c1  : c_st;

            // publish masked h to this group's parity buffer (bypass store)
            short hv = f2bf(h_st);
            short* dst = grp ? h1w : h0w;
            __hip_atomic_store(&dst[m_cg * HID + j_g], hv,
                               __ATOMIC_RELAXED, __HIP_MEMORY_SCOPE_AGENT);
            if (grp == 1 && s >= 1)
                out[(size_t)((s - 1) * BATCH + m_cg) * HID + j_g] = h_st;
        }

        // ---- arrive: drain own stores, then flag (no wbl2, no inv) ----
        __builtin_amdgcn_s_waitcnt(0);
        __syncthreads();
        if (tid == 0)
            __hip_atomic_store(&flags[wg * 4], (unsigned)(s + 1), __ATOMIC_RELAXED,
                               __HIP_MEMORY_SCOPE_AGENT);
    }

    // final h_n / c_n straight from registers (grp0 -> rows 0/2, grp1 -> 1/3)
    {
        const size_t ybase = (size_t)T_STEPS * BATCH * HID;
        const size_t off = (size_t)m_cg * HID + j_g;
        out[ybase + (size_t)grp * BATCH * HID + off]       = h_st;
        out[ybase + (size_t)(2 + grp) * BATCH * HID + off] = c_st;
    }
}

// ---------------- launch ----------------
extern "C" void kernel_launch(void* const* d_in, const int* in_sizes, int n_in,
                              void* d_out, int out_size, void* d_ws, size_t ws_size,
                              hipStream_t stream)
{
    const float* x      = (const float*)d_in[0];
    const int*   length = (const int*)  d_in[1];
    const float* w_ih0  = (const float*)d_in[2];
    const float* w_hh0  = (const float*)d_in[3];
    const float* b0     = (const float*)d_in[4];
    const float* g_ih0  = (const float*)d_in[5];
    const float* bt_ih0 = (const float*)d_in[6];
    const float* g_hh0  = (const float*)d_in[7];
    const float* bt_hh0 = (const float*)d_in[8];
    const float* g_c0   = (const float*)d_in[9];
    const float* bt_c0  = (const float*)d_in[10];
    const float* w_ih1  = (const float*)d_in[11];
    const float* w_hh1  = (const float*)d_in[12];
    const float* b1     = (const float*)d_in[13];
    const float* g_ih1  = (const float*)d_in[14];
    const float* bt_ih1 = (const float*)d_in[15];
    const float* g_hh1  = (const float*)d_in[16];
    const float* bt_hh1 = (const float*)d_in[17];
    const float* g_c1   = (const float*)d_in[18];
    const float* bt_c1  = (const float*)d_in[19];

    char* ws = (char*)d_ws;
    // workspace layout (16B-aligned; total 46,665,728 B -- proven budget)
    unsigned* flags = (unsigned*)(ws + 0);            // 4096 B (256 flags, 16B stride)
    short* h0A   = (short*)(ws + 4096);               // 131072 B
    short* h0B   = (short*)(ws + 135168);             // 131072 B
    short* h1A   = (short*)(ws + 266240);             // 131072 B
    short* h1B   = (short*)(ws + 397312);             // 131072 B
    // ---- end of zeroed region: 528384 ----
    short* xb    = (short*)(ws + 528384);             // 16,777,216 B
    short* wih0T = (short*)(ws + 17305600);           //  4,194,304 B
    short* whh0T = (short*)(ws + 21499904);           //  8,388,608 B
    short* wih1T = (short*)(ws + 29888512);           //  8,388,608 B
    short* whh1T = (short*)(ws + 38277120);           //  8,388,608 B
    // total footprint: 46,665,728 bytes

    // zero flags + h parity buffers (harness re-poisons ws each timed launch)
    (void)hipMemsetAsync(ws, 0, 528384, stream);

    cvt_bf16_kernel<<<2048, 256, 0, stream>>>(x, xb, T_STEPS * BATCH * DIN);

    dim3 tb(32, 8);
    transpose_bf16_kernel<<<dim3(NCOLS / 32, DIN / 32), tb, 0, stream>>>(w_ih0, wih0T, DIN, NCOLS);
    transpose_bf16_kernel<<<dim3(NCOLS / 32, HID / 32), tb, 0, stream>>>(w_hh0, whh0T, HID, NCOLS);
    transpose_bf16_kernel<<<dim3(NCOLS / 32, HID / 32), tb, 0, stream>>>(w_ih1, wih1T, HID, NCOLS);
    transpose_bf16_kernel<<<dim3(NCOLS / 32, HID / 32), tb, 0, stream>>>(w_hh1, whh1T, HID, NCOLS);

    lstm_persist<<<NBLK, TPB, 0, stream>>>(
        length,
        b0, g_ih0, bt_ih0, g_hh0, bt_hh0, g_c0, bt_c0,
        b1, g_ih1, bt_ih1, g_hh1, bt_hh1, g_c1, bt_c1,
        xb, wih0T, whh0T, wih1T, whh1T,
        h0A, h0B, h1A, h1B,
        flags,
        (float*)d_out);
}

// Round 7
// 10339.719 us; speedup vs baseline: 1.0655x; 1.0655x over previous
//
#include <hip/hip_runtime.h>

// ---------------- problem constants ----------------
#define T_STEPS 256
#define BATCH   64
#define DIN     512
#define HID     1024
#define NCOLS   4096   // 4*HID
#define NBLK    256    // persistent blocks (1 per CU)
#define TPB     512    // 8 waves: waves 0-3 = layer0, waves 4-7 = layer1

typedef __attribute__((ext_vector_type(8))) short short8;
typedef __attribute__((ext_vector_type(4))) float float4v;
typedef unsigned long long u64;

union Frag { u64 u[2]; short8 s; };

__device__ __forceinline__ short f2bf(float x) {
    unsigned u = __float_as_uint(x);
    u += 0x7FFFu + ((u >> 16) & 1u);   // RNE
    return (short)(u >> 16);
}
__device__ __forceinline__ float sigmoidf_(float x) { return 1.0f / (1.0f + __expf(-x)); }
__device__ __forceinline__ float tanhf_(float x)    { return 1.0f - 2.0f / (__expf(2.0f * x) + 1.0f); }

// ---------------- prologue kernels ----------------
__global__ void cvt_bf16_kernel(const float* __restrict__ src, short* __restrict__ dst, int n) {
    int i = blockIdx.x * blockDim.x + threadIdx.x;
    int stride = gridDim.x * blockDim.x;
    for (; i < n; i += stride) dst[i] = f2bf(src[i]);
}

// src: R x C fp32 row-major -> dst: C x R bf16 row-major
__global__ void transpose_bf16_kernel(const float* __restrict__ src, short* __restrict__ dst,
                                      int R, int C) {
    __shared__ float tile[32][33];
    int tx = threadIdx.x, ty = threadIdx.y;
    int r0 = blockIdx.y * 32, c0 = blockIdx.x * 32;
#pragma unroll
    for (int i = 0; i < 32; i += 8)
        tile[ty + i][tx] = src[(size_t)(r0 + ty + i) * C + (c0 + tx)];
    __syncthreads();
#pragma unroll
    for (int i = 0; i < 32; i += 8)
        dst[(size_t)(c0 + ty + i) * R + (r0 + tx)] = f2bf(tile[tx][ty + i]);
}

// ---------------- fused persistent LSTM, wave-group layer-parallel ----------
// Round-6 structure (correct; absmax 0.0039): waves 0-3 = layer0 step body,
// waves 4-7 = layer1 step body, concurrent within a superstep. Round-6's
// 11ms regression was NOT structural: __launch_bounds__(512,2) means min 2
// BLOCKS/CU (CUDA semantics) -> 16 waves/CU -> 128-VGPR cap -> massive
// scratch spills (WRITE_SIZE 0.4->2.0 GB, FETCH 0.35->3.3 GB). Round-7 fix:
//  - __launch_bounds__(512, 1): 1 block/CU, 2 waves/SIMD, 256-VGPR cap.
//  - Wih0 staged in static LDS (16 KB, round-5-proven) alongside Whh1
//    (32 KB). Streamed set = Whh0+Wih1 = 2 MB/XCD (L2-resident, proven).
//
// Communication substrate unchanged (proven): parity double-buffers h0A/B,
// h1A/B, memset-zeroed; bypass atomic stores + s_waitcnt(0) drain before
// flag; bypass atomic loads; monotonic flag counters + poll.
// Workspace 46.7 MB (proven budget).
__global__ __launch_bounds__(TPB, 1) void lstm_persist(
    const int* __restrict__ length,
    const float* __restrict__ b0,  const float* __restrict__ g_ih0, const float* __restrict__ bt_ih0,
    const float* __restrict__ g_hh0, const float* __restrict__ bt_hh0,
    const float* __restrict__ g_c0,  const float* __restrict__ bt_c0,
    const float* __restrict__ b1,  const float* __restrict__ g_ih1, const float* __restrict__ bt_ih1,
    const float* __restrict__ g_hh1, const float* __restrict__ bt_hh1,
    const float* __restrict__ g_c1,  const float* __restrict__ bt_c1,
    const short* __restrict__ xb,
    const short* __restrict__ wih0T, const short* __restrict__ whh0T,
    const short* __restrict__ wih1T, const short* __restrict__ whh1T,
    short* __restrict__ h0A, short* __restrict__ h0B,
    short* __restrict__ h1A, short* __restrict__ h1B,
    unsigned* __restrict__ flags,
    float* __restrict__ out)
{
    const int wg   = blockIdx.x;
    const int tid  = threadIdx.x;
    const int wave = tid >> 6;
    const int lane = tid & 63;
    const int nidx = lane & 15;
    const int quad = lane >> 4;
    const int grp  = wave >> 2;          // 0 = layer0, 1 = layer1
    const int rg   = wave & 3;           // row group within the layer

    __shared__ short8 Li0s[1024];        // Wih0 slice, 16 KB (frag order)
    __shared__ short8 Lh1s[2048];        // Whh1 slice, 32 KB (frag order)
    __shared__ float st_s[8][16][17];    // per-wave 16x16 s tile (+pad)
    __shared__ float red_h[8][16][2];    // per-wave column (sum,sumsq) hh
    __shared__ float red_i[8][16][2];    // ... ih
    __shared__ float red_c[8][4][2];     // per-wave (sum,sumsq) for c, 4 j's
    __shared__ unsigned okv[8];          // barrier poll combine

    const int ncol  = wg * 4 + (nidx & 3) + (nidx >> 2) * HID;  // s-col 0..4095
    const int m_row = rg * 16 + nidx;    // A-fragment batch row

    const int mc   = lane & 15;          // c-phase: row within wave
    const int jc   = quad;               // c-phase: which of 4 j's
    const int m_cg = rg * 16 + mc;
    const int j_g  = wg * 4 + jc;
    const int len_c = length[m_cg];
    const float inv64 = 1.0f / 64.0f;

    // ---- one-time LDS staging: Wih0 + Whh1 fragments (f = e*16 + n) ----
    for (int idx = tid; idx < 1024; idx += TPB) {
        int e = idx & 63, n = idx >> 6;
        int ncol_n = wg * 4 + (n & 3) + (n >> 2) * HID;
        Li0s[e * 16 + n] = ((const short8*)wih0T)[(size_t)ncol_n * 64 + e];
    }
    for (int idx = tid; idx < 2048; idx += TPB) {
        int e = idx & 127, n = idx >> 7;
        int ncol_n = wg * 4 + (n & 3) + (n >> 2) * HID;
        Lh1s[e * 16 + n] = ((const short8*)whh1T)[(size_t)ncol_n * 128 + e];
    }
    __syncthreads();

    const int b_off = quad * 16 + nidx;  // LDS fragment offset: kk*64 + b_off

    // streamed B pointers (L2-resident: 2 MB/XCD)
    const short8* Bi1p = (const short8*)wih1T + (size_t)ncol * (HID / 8) + quad;
    const short8* Bh0p = (const short8*)whh0T + (size_t)ncol * (HID / 8) + quad;

    // per-group BN / bias params
    const float gihv = (grp ? g_ih1  : g_ih0 )[ncol];
    const float btih = (grp ? bt_ih1 : bt_ih0)[ncol];
    const float ghhv = (grp ? g_hh1  : g_hh0)[ncol];
    const float bthh = (grp ? bt_hh1 : bt_hh0)[ncol];
    const float bbv  = (grp ? b1     : b0   )[ncol];
    const float gcv  = (grp ? g_c1   : g_c0 )[j_g];
    const float btc  = (grp ? bt_c1  : bt_c0)[j_g];

    float h_st = 0.f, c_st = 0.f;        // this thread's layer-(grp) state

#pragma unroll 1
    for (int s = 0; s <= T_STEPS; ++s) {
        const int p = s & 1;
        const short* h0r = p ? h0A : h0B;   // h0(s-1)   (zeroed at s=0)
        short*       h0w = p ? h0B : h0A;   // <- h0(s)
        const short* h1r = p ? h1B : h1A;   // h1(s-2)   (zeroed at s<=1)
        short*       h1w = p ? h1A : h1B;   // <- h1(s-1)

        // ---- pre-barrier: grp0's ih0 GEMM (x cached, Wih0 from LDS) ----
        float4v acc_i = {0.f, 0.f, 0.f, 0.f};
        if (grp == 0 && s < T_STEPS) {
            const short8* Axp = (const short8*)xb + (((size_t)(s * BATCH + m_row) * DIN) >> 3) + quad;
            float4v a0 = {0.f,0.f,0.f,0.f}, a1 = {0.f,0.f,0.f,0.f};
#pragma unroll
            for (int kk = 0; kk < 16; ++kk) {
                short8 b = Li0s[kk * 64 + b_off];
                if (kk & 1) a1 = __builtin_amdgcn_mfma_f32_16x16x32_bf16(Axp[kk * 4], b, a1, 0, 0, 0);
                else        a0 = __builtin_amdgcn_mfma_f32_16x16x32_bf16(Axp[kk * 4], b, a0, 0, 0, 0);
            }
            acc_i = a0 + a1;
        }

        // ---- grid barrier: all blocks finished superstep s-1 ----
        if (s > 0) {
            const unsigned need = (unsigned)s;
            for (;;) {
                unsigned f = __hip_atomic_load(&flags[(tid & 255) * 4], __ATOMIC_RELAXED,
                                               __HIP_MEMORY_SCOPE_AGENT);
                unsigned long long bal = __ballot(f >= need);
                if (lane == 0) okv[wave] = (bal + 1ull == 0ull);
                __syncthreads();
                bool all8 = okv[0] && okv[1] && okv[2] && okv[3]
                         && okv[4] && okv[5] && okv[6] && okv[7];
                __syncthreads();
                if (all8) break;
                __builtin_amdgcn_s_sleep(2);
            }
            asm volatile("" ::: "memory");   // no load motion across the barrier
        }

        // ---- post-barrier GEMMs (bypass loads of h state) ----
        float4v acc_h = {0.f,0.f,0.f,0.f};
        if (grp == 0) {
            // hh0: A = h0(s-1), B = Whh0 streamed
            u64 A2[64];
            const u64* hp = (const u64*)h0r + (size_t)m_row * (HID / 4) + quad * 2;
#pragma unroll
            for (int kk = 0; kk < 32; ++kk) {
                A2[2 * kk]     = __hip_atomic_load(hp + kk * 8,     __ATOMIC_RELAXED, __HIP_MEMORY_SCOPE_AGENT);
                A2[2 * kk + 1] = __hip_atomic_load(hp + kk * 8 + 1, __ATOMIC_RELAXED, __HIP_MEMORY_SCOPE_AGENT);
            }
            float4v h0a = {0.f,0.f,0.f,0.f}, h0b = {0.f,0.f,0.f,0.f};
#pragma unroll
            for (int kk = 0; kk < 32; ++kk) {
                Frag fa; fa.u[0] = A2[2 * kk]; fa.u[1] = A2[2 * kk + 1];
                if (kk & 1) h0b = __builtin_amdgcn_mfma_f32_16x16x32_bf16(fa.s, Bh0p[kk * 4], h0b, 0, 0, 0);
                else        h0a = __builtin_amdgcn_mfma_f32_16x16x32_bf16(fa.s, Bh0p[kk * 4], h0a, 0, 0, 0);
            }
            acc_h = h0a + h0b;
        } else {
            // ih1: A = h0(s-1) (=y0(t1)), B = Wih1 streamed
            // hh1: A = h1(s-2),           B = Whh1 from LDS
            u64 A2[64];
            u64 C2[64];
            const u64* hp = (const u64*)h0r + (size_t)m_row * (HID / 4) + quad * 2;
            const u64* cp = (const u64*)h1r + (size_t)m_row * (HID / 4) + quad * 2;
#pragma unroll
            for (int kk = 0; kk < 32; ++kk) {
                A2[2 * kk]     = __hip_atomic_load(hp + kk * 8,     __ATOMIC_RELAXED, __HIP_MEMORY_SCOPE_AGENT);
                A2[2 * kk + 1] = __hip_atomic_load(hp + kk * 8 + 1, __ATOMIC_RELAXED, __HIP_MEMORY_SCOPE_AGENT);
            }
#pragma unroll
            for (int kk = 0; kk < 32; ++kk) {
                C2[2 * kk]     = __hip_atomic_load(cp + kk * 8,     __ATOMIC_RELAXED, __HIP_MEMORY_SCOPE_AGENT);
                C2[2 * kk + 1] = __hip_atomic_load(cp + kk * 8 + 1, __ATOMIC_RELAXED, __HIP_MEMORY_SCOPE_AGENT);
            }
            float4v i1a = {0.f,0.f,0.f,0.f}, i1b = {0.f,0.f,0.f,0.f};
#pragma unroll
            for (int kk = 0; kk < 32; ++kk) {
                Frag fa; fa.u[0] = A2[2 * kk]; fa.u[1] = A2[2 * kk + 1];
                if (kk & 1) i1b = __builtin_amdgcn_mfma_f32_16x16x32_bf16(fa.s, Bi1p[kk * 4], i1b, 0, 0, 0);
                else        i1a = __builtin_amdgcn_mfma_f32_16x16x32_bf16(fa.s, Bi1p[kk * 4], i1a, 0, 0, 0);
            }
            acc_i = i1a + i1b;
            float4v ha = {0.f,0.f,0.f,0.f}, hb = {0.f,0.f,0.f,0.f};
            float4v hc = {0.f,0.f,0.f,0.f}, hd = {0.f,0.f,0.f,0.f};
#pragma unroll
            for (int kk = 0; kk < 32; ++kk) {
                Frag fa; fa.u[0] = C2[2 * kk]; fa.u[1] = C2[2 * kk + 1];
                short8 bh = Lh1s[kk * 64 + b_off];
                switch (kk & 3) {
                    case 0:  ha = __builtin_amdgcn_mfma_f32_16x16x32_bf16(fa.s, bh, ha, 0, 0, 0); break;
                    case 1:  hb = __builtin_amdgcn_mfma_f32_16x16x32_bf16(fa.s, bh, hb, 0, 0, 0); break;
                    case 2:  hc = __builtin_amdgcn_mfma_f32_16x16x32_bf16(fa.s, bh, hc, 0, 0, 0); break;
                    default: hd = __builtin_amdgcn_mfma_f32_16x16x32_bf16(fa.s, bh, hd, 0, 0, 0); break;
                }
            }
            acc_h = (ha + hb) + (hc + hd);
        }

        // ========== unified BN + gates (identical sync sequence, both grps) ==========
        {
            float s1h = acc_h[0] + acc_h[1] + acc_h[2] + acc_h[3];
            float s2h = acc_h[0]*acc_h[0] + acc_h[1]*acc_h[1] + acc_h[2]*acc_h[2] + acc_h[3]*acc_h[3];
            float s1i = acc_i[0] + acc_i[1] + acc_i[2] + acc_i[3];
            float s2i = acc_i[0]*acc_i[0] + acc_i[1]*acc_i[1] + acc_i[2]*acc_i[2] + acc_i[3]*acc_i[3];
            s1h += __shfl_xor(s1h, 16); s1h += __shfl_xor(s1h, 32);
            s2h += __shfl_xor(s2h, 16); s2h += __shfl_xor(s2h, 32);
            s1i += __shfl_xor(s1i, 16); s1i += __shfl_xor(s1i, 32);
            s2i += __shfl_xor(s2i, 16); s2i += __shfl_xor(s2i, 32);
            if (quad == 0) {
                red_h[wave][nidx][0] = s1h; red_h[wave][nidx][1] = s2h;
                red_i[wave][nidx][0] = s1i; red_i[wave][nidx][1] = s2i;
            }
            __syncthreads();
            float th = 0.f, qh = 0.f, ti = 0.f, qi = 0.f;
#pragma unroll
            for (int w = 0; w < 4; ++w) {
                th += red_h[grp * 4 + w][nidx][0]; qh += red_h[grp * 4 + w][nidx][1];
                ti += red_i[grp * 4 + w][nidx][0]; qi += red_i[grp * 4 + w][nidx][1];
            }
            float muh = th * inv64, vah = qh * inv64 - muh * muh;
            float mui = ti * inv64, vai = qi * inv64 - mui * mui;
            float rsh = rsqrtf(vah + 1e-5f), rsi = rsqrtf(vai + 1e-5f);
#pragma unroll
            for (int r = 0; r < 4; ++r) {
                float sv = ghhv * (acc_h[r] - muh) * rsh + bthh
                         + gihv * (acc_i[r] - mui) * rsi + btih + bbv;
                st_s[wave][quad * 4 + r][nidx] = sv;
            }
            __syncthreads();

            float fv = st_s[wave][mc][jc];
            float iv = st_s[wave][mc][4 + jc];
            float ov = st_s[wave][mc][8 + jc];
            float gv = st_s[wave][mc][12 + jc];
            float c1 = sigmoidf_(fv) * c_st + sigmoidf_(iv) * tanhf_(gv);

            float cs = c1, cq = c1 * c1;
            cs += __shfl_xor(cs, 1); cs += __shfl_xor(cs, 2);
            cs += __shfl_xor(cs, 4); cs += __shfl_xor(cs, 8);
            cq += __shfl_xor(cq, 1); cq += __shfl_xor(cq, 2);
            cq += __shfl_xor(cq, 4); cq += __shfl_xor(cq, 8);
            if (mc == 0) { red_c[wave][jc][0] = cs; red_c[wave][jc][1] = cq; }
            __syncthreads();
            float tc = 0.f, qc = 0.f;
#pragma unroll
            for (int w = 0; w < 4; ++w) { tc += red_c[grp * 4 + w][jc][0]; qc += red_c[grp * 4 + w][jc][1]; }
            float muc = tc * inv64, vac = qc * inv64 - muc * muc;
            float bnc = gcv * (c1 - muc) * rsqrtf(vac + 1e-5f) + btc;
            float h1v = sigmoidf_(ov) * tanhf_(bnc);

            const int tt = grp ? (s - 1) : s;       // this group's timestep
            bool mk = (tt >= 0) && (tt < len_c);
            h_st = mk ? h1v : h_st;
            c_st = mk ? c1  : c_st;

            // publish masked h to this group's parity buffer (bypass store)
            short hv = f2bf(h_st);
            short* dst = grp ? h1w : h0w;
            __hip_atomic_store(&dst[m_cg * HID + j_g], hv,
                               __ATOMIC_RELAXED, __HIP_MEMORY_SCOPE_AGENT);
            if (grp == 1 && s >= 1)
                out[(size_t)((s - 1) * BATCH + m_cg) * HID + j_g] = h_st;
        }

        // ---- arrive: drain own stores, then flag (no wbl2, no inv) ----
        __builtin_amdgcn_s_waitcnt(0);
        __syncthreads();
        if (tid == 0)
            __hip_atomic_store(&flags[wg * 4], (unsigned)(s + 1), __ATOMIC_RELAXED,
                               __HIP_MEMORY_SCOPE_AGENT);
    }

    // final h_n / c_n straight from registers (grp0 -> rows 0/2, grp1 -> 1/3)
    {
        const size_t ybase = (size_t)T_STEPS * BATCH * HID;
        const size_t off = (size_t)m_cg * HID + j_g;
        out[ybase + (size_t)grp * BATCH * HID + off]       = h_st;
        out[ybase + (size_t)(2 + grp) * BATCH * HID + off] = c_st;
    }
}

// ---------------- launch ----------------
extern "C" void kernel_launch(void* const* d_in, const int* in_sizes, int n_in,
                              void* d_out, int out_size, void* d_ws, size_t ws_size,
                              hipStream_t stream)
{
    const float* x      = (const float*)d_in[0];
    const int*   length = (const int*)  d_in[1];
    const float* w_ih0  = (const float*)d_in[2];
    const float* w_hh0  = (const float*)d_in[3];
    const float* b0     = (const float*)d_in[4];
    const float* g_ih0  = (const float*)d_in[5];
    const float* bt_ih0 = (const float*)d_in[6];
    const float* g_hh0  = (const float*)d_in[7];
    const float* bt_hh0 = (const float*)d_in[8];
    const float* g_c0   = (const float*)d_in[9];
    const float* bt_c0  = (const float*)d_in[10];
    const float* w_ih1  = (const float*)d_in[11];
    const float* w_hh1  = (const float*)d_in[12];
    const float* b1     = (const float*)d_in[13];
    const float* g_ih1  = (const float*)d_in[14];
    const float* bt_ih1 = (const float*)d_in[15];
    const float* g_hh1  = (const float*)d_in[16];
    const float* bt_hh1 = (const float*)d_in[17];
    const float* g_c1   = (const float*)d_in[18];
    const float* bt_c1  = (const float*)d_in[19];

    char* ws = (char*)d_ws;
    // workspace layout (16B-aligned; total 46,665,728 B -- proven budget)
    unsigned* flags = (unsigned*)(ws + 0);            // 4096 B (256 flags, 16B stride)
    short* h0A   = (short*)(ws + 4096);               // 131072 B
    short* h0B   = (short*)(ws + 135168);             // 131072 B
    short* h1A   = (short*)(ws + 266240);             // 131072 B
    short* h1B   = (short*)(ws + 397312);             // 131072 B
    // ---- end of zeroed region: 528384 ----
    short* xb    = (short*)(ws + 528384);             // 16,777,216 B
    short* wih0T = (short*)(ws + 17305600);           //  4,194,304 B
    short* whh0T = (short*)(ws + 21499904);           //  8,388,608 B
    short* wih1T = (short*)(ws + 29888512);           //  8,388,608 B
    short* whh1T = (short*)(ws + 38277120);           //  8,388,608 B
    // total footprint: 46,665,728 bytes

    // zero flags + h parity buffers (harness re-poisons ws each timed launch)
    (void)hipMemsetAsync(ws, 0, 528384, stream);

    cvt_bf16_kernel<<<2048, 256, 0, stream>>>(x, xb, T_STEPS * BATCH * DIN);

    dim3 tb(32, 8);
    transpose_bf16_kernel<<<dim3(NCOLS / 32, DIN / 32), tb, 0, stream>>>(w_ih0, wih0T, DIN, NCOLS);
    transpose_bf16_kernel<<<dim3(NCOLS / 32, HID / 32), tb, 0, stream>>>(w_hh0, whh0T, HID, NCOLS);
    transpose_bf16_kernel<<<dim3(NCOLS / 32, HID / 32), tb, 0, stream>>>(w_ih1, wih1T, HID, NCOLS);
    transpose_bf16_kernel<<<dim3(NCOLS / 32, HID / 32), tb, 0, stream>>>(w_hh1, whh1T, HID, NCOLS);

    lstm_persist<<<NBLK, TPB, 0, stream>>>(
        length,
        b0, g_ih0, bt_ih0, g_hh0, bt_hh0, g_c0, bt_c0,
        b1, g_ih1, bt_ih1, g_hh1, bt_hh1, g_c1, bt_c1,
        xb, wih0T, whh0T, wih1T, whh1T,
        h0A, h0B, h1A, h1B,
        flags,
        (float*)d_out);
}